// Round 20
// baseline (223.632 us; speedup 1.0000x reference)
//
#include <hip/hip_runtime.h>
#include <hip/hip_bf16.h>

// 2-layer LSTM (H=32, T=512, I=1) + FC(1) + ReLU, fused, ZERO-SELECT,
// TWO INDEPENDENT BARRIER DOMAINS PER CU (R17 concept, fixed).
// 8 batches/block, 512 blocks x 8 waves -> 2 blocks/CU = 4 waves/SIMD in
// two independent barrier domains: when block A stalls at its per-step
// barrier / LDS-read, block B's waves issue (the champion's waves are
// phase-locked; wall ~= issue + chain + barrier with no overlap).
// R17's flaw is removed: col = 2s + q puts the replica partner at lane^1,
// so h-pair packing is one full-rate v_mov_dpp quad_perm + cvt_pk -- NO
// ds_swizzle round-trip on the recurrence path. Replica q owns tile q
// (4-cndmask select); both tiles share one C-in keyed to the owned unit.
// Carried from champion: adjacent-unit tiles, L1 lag-2 with h0 register
// prefetch (4-parity ring), bias+x folded into MFMA C-in, parallel P/Q
// L1 MFMAs, merged-rcp CELL (7 trans), one __syncthreads per step,
// pre-zeroed LDS.

typedef __attribute__((ext_vector_type(8))) short bf16x8;
typedef __attribute__((ext_vector_type(4))) float f32x4;
typedef __attribute__((ext_vector_type(4))) int   i32x4;

#define HID 32
#define SEQ 512
#define L2E 1.4426950408889634f
#define LSTR 20   // LDS h-row stride in dwords (16 used + 4 pad)

static __device__ __forceinline__ float fexp2(float x){ return __builtin_amdgcn_exp2f(x); }
static __device__ __forceinline__ float frcp (float x){ return __builtin_amdgcn_rcpf(x); }
static __device__ __forceinline__ short f2bf(float f){
  unsigned u = __builtin_bit_cast(unsigned, f);
  u = (u + 0x7fffu + ((u >> 16) & 1u)) >> 16;
  return (short)u;
}

// fused LSTM cell, merged-rcp form. Gates pre-scaled (i,f,o by -log2e;
// g by +2log2e):  I=e^-i, F=e^-f, O=e^-o, G=e^{2g}.
#define CELL(gi, gf, gg, go, cvr, hout) do {                         \
  const float I_ = fexp2(gi), G_ = fexp2(gg);                        \
  const float F_ = fexp2(gf), O_ = fexp2(go);                        \
  const float a_ = 1.f + I_, b_ = 1.f + G_, c_ = 1.f + F_;           \
  const float P1_ = a_ * b_;                                         \
  const float R_  = frcp(c_ * P1_);                                  \
  const float fv_ = P1_ * R_;                                        \
  const float ig_ = (G_ - 1.f) * (c_ * R_);                          \
  (cvr) = fmaf(fv_, (cvr), ig_);                                     \
  const float C2_ = fexp2((cvr) * (2.f * L2E));                      \
  (hout) = (C2_ - 1.f) * frcp((1.f + O_) * (1.f + C2_));             \
} while (0)

// pair-pack: neighbor lane^1 via DPP quad_perm [1,0,3,2] (full-rate VALU)
#define HPACK(hv, pk) do {                                                    \
  const float hp_ = __builtin_bit_cast(float,                                 \
      __builtin_amdgcn_mov_dpp(__builtin_bit_cast(int, (hv)), 0xB1, 0xF, 0xF, false)); \
  asm("v_cvt_pk_bf16_f32 %0, %1, %2" : "=v"(pk) : "v"(hv), "v"(hp_));         \
} while (0)

__global__ __launch_bounds__(512, 4) void lstm2_db3_kernel(
    const float* __restrict__ x,
    const float* __restrict__ Wih0, const float* __restrict__ Whh0,
    const float* __restrict__ bih0, const float* __restrict__ bhh0,
    const float* __restrict__ Wih1, const float* __restrict__ Whh1,
    const float* __restrict__ bih1, const float* __restrict__ bhh1,
    const float* __restrict__ Wfc, const float* __restrict__ bfc,
    float* __restrict__ out)
{
  const int tid = threadIdx.x;
  const int w   = tid >> 6;          // 0-3: L0 groups; 4-7: L1 groups
  const int l   = tid & 63;
  const int m   = l >> 4;            // k-group; D rows 4m..4m+3
  const int col = l & 15;            // MFMA N col = 2s + q
  const int s   = col >> 1;          // batch slot (8 batches/block)
  const int q   = col & 1;           // replica bit -> owned TILE
  const int V   = w & 3;             // unit group: units 8V..8V+7
  const bool isL1 = (w >= 4);
  const bool qb = (q != 0);
  const int uc = 8 * V + 2 * m + q;  // owned cell unit

  __shared__ int   bufH0[4][8 * LSTR];   // 4 parities (lag-2 prefetch)
  __shared__ int   bufH1[2][8 * LSTR];
  __shared__ float bufFC[4][8];

  // zero-init exchange buffers (kills all t=0 special cases)
  for (int i = tid; i < 4 * 8 * LSTR; i += 512) ((int*)bufH0)[i] = 0;
  for (int i = tid; i < 2 * 8 * LSTR; i += 512) ((int*)bufH1)[i] = 0;
  __syncthreads();

  // ---- weights: tile t row rho = gate(rho&3) of unit 8V+2*(rho>>2)+t.
  //      Lane supplies A row = col. Pre-scaled: i,f,o -> -log2e; g -> +2log2e.
  const float* Wrec = isL1 ? Whh1 : Whh0;
  const float* Bi   = isL1 ? bih1 : bih0;
  const float* Bh   = isL1 ? bhh1 : bhh0;
  const int   gcol  = col & 3;             // gate type this lane's A-row feeds
  const float scA   = (gcol == 2) ? (2.0f * L2E) : (-L2E);
  bf16x8 wfR[2], wfI[2];
  #pragma unroll
  for (int t = 0; t < 2; ++t) {
    const int ga = gcol * 32 + 8 * V + 2 * (col >> 2) + t;  // A-row's gate row
    #pragma unroll
    for (int j = 0; j < 8; ++j) {
      wfR[t][j] = f2bf(scA * Wrec[ga * HID + (8 * m + j)]);
      wfI[t][j] = isL1 ? f2bf(scA * Wih1[ga * HID + (8 * m + j)]) : (short)0;
    }
  }
  // C-in keyed to the OWNED unit only (non-owned tile's D is discarded)
  f32x4 cb;
  float w0x[4];
  #pragma unroll
  for (int rr = 0; rr < 4; ++rr) {
    const float sc = (rr == 2) ? (2.0f * L2E) : (-L2E);
    cb[rr]  = sc * (Bi[rr * 32 + uc] + Bh[rr * 32 + uc]);
    w0x[rr] = isL1 ? 0.f : sc * Wih0[rr * 32 + uc];
  }
  const float wfc = isL1 ? Wfc[uc] : 0.f;

  float cv = 0.f, hn = 0.f;
  i32x4 h0pre = {0, 0, 0, 0};        // L1: h0(i-2) register prefetch
  const float* xb = x + (size_t)(blockIdx.x * 8 + s) * SEQ;
  const int  rd = s * LSTR + 4 * m;            // b128 read: units 8m..8m+7
  const int  wb = s * LSTR + 4 * V + m;        // b32 write: own unit pair
  const bool wr = (q == 0);                    // q=0 lanes write

  float4 xcur = {0.f, 0.f, 0.f, 0.f};
  if (!isL1) xcur = *reinterpret_cast<const float4*>(xb);   // k = 0

  for (int k = 0; k < SEQ / 4; ++k) {
    float4 xnext = {0.f, 0.f, 0.f, 0.f};
    if (!isL1 && k + 1 < SEQ / 4)
      xnext = *reinterpret_cast<const float4*>(xb + (k + 1) * 4);  // prefetch
    #pragma unroll
    for (int uu = 0; uu < 4; ++uu) {
      if (!isL1) {
        // ---- L0: h0(i) from h0(i-1) in bufH0[(i-1)&3] ----
        const i32x4 hv = *(const i32x4*)&bufH0[(uu + 3) & 3][rd];
        const bf16x8 hf = __builtin_bit_cast(bf16x8, hv);
        const float xt = (uu == 0) ? xcur.x : (uu == 1) ? xcur.y
                       : (uu == 2) ? xcur.z : xcur.w;
        f32x4 cbx;
        #pragma unroll
        for (int rr = 0; rr < 4; ++rr) cbx[rr] = fmaf(w0x[rr], xt, cb[rr]);
        f32x4 A0, A1;
        A0 = __builtin_amdgcn_mfma_f32_16x16x32_bf16(wfR[0], hf, cbx, 0, 0, 0);
        A1 = __builtin_amdgcn_mfma_f32_16x16x32_bf16(wfR[1], hf, cbx, 0, 0, 0);
        const f32x4 A = qb ? A1 : A0;   // owned tile's (i,f,g,o)
        CELL(A[0], A[1], A[2], A[3], cv, hn);
        int pk;
        HPACK(hn, pk);
        if (wr) bufH0[uu][wb] = pk;    // pair (8V+2m, 8V+2m+1) = slot 4V+m
      } else {
        const bool doC = (uu >= 2) || (k > 0);   // compute h1(i-2)
        const bool doP = (uu >= 1) || (k > 0);   // prefetch h0(i-1)
        i32x4 h1v = {0, 0, 0, 0};
        if (doC) h1v = *(const i32x4*)&bufH1[(uu + 1) & 1][rd];  // h1(i-3)
        i32x4 h0next = h0pre;
        if (doP) h0next = *(const i32x4*)&bufH0[(uu + 3) & 3][rd]; // h0(i-1)
        if (doC) {
          const bf16x8 h0f = __builtin_bit_cast(bf16x8, h0pre);
          const bf16x8 h1f = __builtin_bit_cast(bf16x8, h1v);
          const f32x4 z4 = {0.f, 0.f, 0.f, 0.f};
          f32x4 P0, P1, Q0, Q1;
          P0 = __builtin_amdgcn_mfma_f32_16x16x32_bf16(wfI[0], h0f, cb, 0, 0, 0);
          P1 = __builtin_amdgcn_mfma_f32_16x16x32_bf16(wfI[1], h0f, cb, 0, 0, 0);
          Q0 = __builtin_amdgcn_mfma_f32_16x16x32_bf16(wfR[0], h1f, z4, 0, 0, 0);
          Q1 = __builtin_amdgcn_mfma_f32_16x16x32_bf16(wfR[1], h1f, z4, 0, 0, 0);
          const f32x4 A0 = P0 + Q0;     // independent MFMAs, merged by v_add
          const f32x4 A1 = P1 + Q1;
          const f32x4 A = qb ? A1 : A0;
          CELL(A[0], A[1], A[2], A[3], cv, hn);
          int pk;
          HPACK(hn, pk);
          if (wr) bufH1[uu & 1][wb] = pk;  // h1(i-2) -> slot (i-2)&1 = i&1
        }
        h0pre = h0next;
      }
      __syncthreads();
    }
    xcur = xnext;
  }

  // ---- epilogue: L1 still owes h1(510), h1(511) ----
  if (isL1) {
    // h1(510) = f(h0(510)=h0pre, h1(509)=bufH1[1])
    const i32x4 h1v = *(const i32x4*)&bufH1[1][rd];
    const bf16x8 h0f = __builtin_bit_cast(bf16x8, h0pre);
    const bf16x8 h1f = __builtin_bit_cast(bf16x8, h1v);
    f32x4 A0, A1;
    A0 = __builtin_amdgcn_mfma_f32_16x16x32_bf16(wfI[0], h0f, cb, 0, 0, 0);
    A1 = __builtin_amdgcn_mfma_f32_16x16x32_bf16(wfI[1], h0f, cb, 0, 0, 0);
    A0 = __builtin_amdgcn_mfma_f32_16x16x32_bf16(wfR[0], h1f, A0, 0, 0, 0);
    A1 = __builtin_amdgcn_mfma_f32_16x16x32_bf16(wfR[1], h1f, A1, 0, 0, 0);
    const f32x4 A = qb ? A1 : A0;
    CELL(A[0], A[1], A[2], A[3], cv, hn);
    int pk;
    HPACK(hn, pk);
    if (wr) bufH1[0][wb] = pk;         // h1(510)
  }
  __syncthreads();
  if (isL1) {
    // h1(511) = f(h0(511)=bufH0[3], h1(510)=bufH1[0]); then FC partial
    const i32x4 h0v = *(const i32x4*)&bufH0[3][rd];
    const i32x4 h1v = *(const i32x4*)&bufH1[0][rd];
    const bf16x8 h0f = __builtin_bit_cast(bf16x8, h0v);
    const bf16x8 h1f = __builtin_bit_cast(bf16x8, h1v);
    f32x4 A0, A1;
    A0 = __builtin_amdgcn_mfma_f32_16x16x32_bf16(wfI[0], h0f, cb, 0, 0, 0);
    A1 = __builtin_amdgcn_mfma_f32_16x16x32_bf16(wfI[1], h0f, cb, 0, 0, 0);
    A0 = __builtin_amdgcn_mfma_f32_16x16x32_bf16(wfR[0], h1f, A0, 0, 0, 0);
    A1 = __builtin_amdgcn_mfma_f32_16x16x32_bf16(wfR[1], h1f, A1, 0, 0, 0);
    const f32x4 A = qb ? A1 : A0;
    CELL(A[0], A[1], A[2], A[3], cv, hn);
    float part = hn * wfc;
    part += __shfl_xor(part, 1);    // sum over q (unit pair)
    part += __shfl_xor(part, 16);   // sum over m
    part += __shfl_xor(part, 32);
    if (l < 16 && (l & 1) == 0) bufFC[V][l >> 1] = part;  // m=0,q=0: s=l>>1
  }
  __syncthreads();
  if (w == 4 && l < 8) {
    const float o = bufFC[0][l] + bufFC[1][l] + bufFC[2][l] + bufFC[3][l] + bfc[0];
    out[blockIdx.x * 8 + l] = o > 0.f ? o : 0.f;
  }
}

extern "C" void kernel_launch(void* const* d_in, const int* in_sizes, int n_in,
                              void* d_out, int out_size, void* d_ws, size_t ws_size,
                              hipStream_t stream) {
  const float* x    = (const float*)d_in[0];
  const float* Wih0 = (const float*)d_in[1];
  const float* Whh0 = (const float*)d_in[2];
  const float* bih0 = (const float*)d_in[3];
  const float* bhh0 = (const float*)d_in[4];
  const float* Wih1 = (const float*)d_in[5];
  const float* Whh1 = (const float*)d_in[6];
  const float* bih1 = (const float*)d_in[7];
  const float* bhh1 = (const float*)d_in[8];
  const float* Wfc  = (const float*)d_in[9];
  const float* bfc  = (const float*)d_in[10];

  const int B = 4096;
  const int grid = B / 8;   // 512 blocks x 8 waves -> 2 blocks/CU,
                            // two independent barrier domains per CU
  lstm2_db3_kernel<<<grid, 512, 0, stream>>>(
      x, Wih0, Whh0, bih0, bhh0, Wih1, Whh1, bih1, bhh1, Wfc, bfc,
      (float*)d_out);
}